// Round 6
// baseline (287.569 us; speedup 1.0000x reference)
//
#include <hip/hip_runtime.h>

// IBRNet aggregator R6: single fused MFMA kernel (f16 in, fp32 acc).
// Block = 128 threads (2 waves) = 64 cols = 8 voxels x 8 views, col = vi*8+n.
// Each wave owns N-tiles {2w, 2w+1} (16 cols each).
// Y[col][k] f16, KP=104 (52 dwords, stride 20 mod 32 -> b128 B-reads 2-way
// free). Weights stay fp32 in global; A-fragments are converted to f16 in
// registers at load (L1-hot). Stats (mean2/var2/wm) go to a separate fp32
// LDS buffer with stride 66 dwords (== 2 mod 32) so the stat layer reads
// broadcast on distinct banks. All b16 LDS traffic is paired into b32 (h2).
//
// Y slot timeline (k ranges):
//   A1: features+rde -> [64:96); mean->[0:32) var->[32:64)
//   base1 reads [0:96) -> h -> [0:64)
//   base2 reads [0:64) -> x -> [64:96), x*wt -> [0:32)
//   vis1 reads [0:32)  -> hv -> [32:64)
//   vis2 reads [32:64) -> x_res -> [0:32), visn (row 32)
//   x-update: x+=x_res -> [64:96), x*visn -> [0:32)
//   vis2_1 reads [0:32) -> hv2 -> [32:64); vis2_2 (VALU) -> visv
//   mean2/var2 (VALU) read [64:96) -> stats (fp32); stat layer (VALU) -> out.

#define G3 32768
#define KP 104

typedef _Float16 h8 __attribute__((ext_vector_type(8)));
typedef _Float16 h4 __attribute__((ext_vector_type(4)));
typedef _Float16 h2 __attribute__((ext_vector_type(2)));
typedef float f4 __attribute__((ext_vector_type(4)));
typedef float f2 __attribute__((ext_vector_type(2)));

__device__ __forceinline__ float eluf(float x) {
    return x > 0.0f ? x : __expf(x) - 1.0f;
}
__device__ __forceinline__ float sigmoidf(float x) {
    return 1.0f / (1.0f + __expf(-x));
}
__device__ __forceinline__ h8 h8zero() {
    h8 r;
#pragma unroll
    for (int i = 0; i < 8; ++i) r[i] = (_Float16)0.0f;
    return r;
}
__device__ __forceinline__ h8 afrag_f32(const float* __restrict__ p) {
    f4 x0 = *(const f4*)(p);
    f4 x1 = *(const f4*)(p + 4);
    h8 r;
    r[0] = (_Float16)x0[0]; r[1] = (_Float16)x0[1];
    r[2] = (_Float16)x0[2]; r[3] = (_Float16)x0[3];
    r[4] = (_Float16)x1[0]; r[5] = (_Float16)x1[1];
    r[6] = (_Float16)x1[2]; r[7] = (_Float16)x1[3];
    return r;
}

// One layer: load B-frags for both tiles, then per M-tile convert the fp32
// weight A-frag in registers and MFMA. rowlim masks nonexistent rows (vis2).
template <int K, int KS, int MT>
__device__ __forceinline__ void mfma_layer(const float* __restrict__ W,
                                           const _Float16* __restrict__ Y,
                                           int srck0, int rowlim, int wave,
                                           int lane, f4 acc[2][4]) {
    const int q = lane >> 4, nlo = lane & 15;
    h8 bf[2][KS];
#pragma unroll
    for (int j = 0; j < 2; ++j) {
        const int col = (wave * 2 + j) * 16 + nlo;
        const _Float16* yc = Y + col * KP + srck0 + q * 8;
#pragma unroll
        for (int kt = 0; kt < KS; ++kt) bf[j][kt] = *(const h8*)(yc + kt * 32);
    }
#pragma unroll
    for (int mt = 0; mt < MT; ++mt) {
        const int row = mt * 16 + nlo;
        h8 af[KS];
#pragma unroll
        for (int kt = 0; kt < KS; ++kt)
            af[kt] = (row < rowlim)
                         ? afrag_f32(W + row * K + q * 8 + kt * 32)
                         : h8zero();
#pragma unroll
        for (int j = 0; j < 2; ++j)
#pragma unroll
            for (int kt = 0; kt < KS; ++kt)
                acc[j][mt] = __builtin_amdgcn_mfma_f32_16x16x32_f16(
                    af[kt], bf[j][kt], acc[j][mt], 0, 0, 0);
    }
}

template <int MT>
__device__ __forceinline__ void epi_store(f4 acc[2][4],
                                          const float* __restrict__ bias,
                                          _Float16* __restrict__ Y, int dstk0,
                                          int wave, int lane) {
    const int q = lane >> 4, nlo = lane & 15;
#pragma unroll
    for (int j = 0; j < 2; ++j) {
        const int col = (wave * 2 + j) * 16 + nlo;
#pragma unroll
        for (int mt = 0; mt < MT; ++mt) {
            f4 bb = *(const f4*)(bias + mt * 16 + q * 4);
            f4 v = acc[j][mt];
            h4 hv;
#pragma unroll
            for (int r = 0; r < 4; ++r) hv[r] = (_Float16)eluf(v[r] + bb[r]);
            *(h4*)(Y + col * KP + dstk0 + mt * 16 + q * 4) = hv;
        }
    }
}

__global__ __launch_bounds__(128) void ibr_mfma(
    const float* __restrict__ features, const float* __restrict__ mask,
    const float* __restrict__ vdepth, const float* __restrict__ vdir,
    const float* __restrict__ rde_w1, const float* __restrict__ rde_b1,
    const float* __restrict__ rde_w2, const float* __restrict__ rde_b2,
    const float* __restrict__ base_w1, const float* __restrict__ base_b1,
    const float* __restrict__ base_w2, const float* __restrict__ base_b2,
    const float* __restrict__ vis_w1, const float* __restrict__ vis_b1,
    const float* __restrict__ vis_w2, const float* __restrict__ vis_b2,
    const float* __restrict__ vis2_w1, const float* __restrict__ vis2_b1,
    const float* __restrict__ vis2_w2, const float* __restrict__ vis2_b2,
    const float* __restrict__ stat_w, const float* __restrict__ stat_b,
    float* __restrict__ out) {
    __shared__ _Float16 Y[64 * KP];     // 13312 B
    __shared__ float stats[8 * 66];     // fp32 mean2/var2/wm, stride 66
    __shared__ float mval[64], wtc[64], visn_s[64], visv_s[64], wt2c[64];
    __shared__ float sA_v[8], wm_v[8];

    const int tid = threadIdx.x;
    const int lane = tid & 63;
    const int wave = tid >> 6;
    const int bb = blockIdx.x;
    const int b = bb >> 12;            // 4096 blocks per batch
    const int i = bb & 4095;
    // XCD swizzle: same-XCD blocks (i = xcd + 8*slot) cover contiguous v.
    const int v0 = (((i & 7) << 9) | (i >> 3)) << 3;  // 8 voxels per block

    // ---- A1: features -> Y[col][64+c] (h2 stores); mask -> mval ------------
    {
        const int n = tid >> 4;           // 0..7
        const int cp = (tid & 15) * 2;    // even channel
        const float* fp0 = features + (((b * 8 + n) * 32 + cp) << 15) + v0;
        f4 a0 = *(const f4*)(fp0);
        f4 a1 = *(const f4*)(fp0 + 4);
        f4 b0v = *(const f4*)(fp0 + G3);
        f4 b1v = *(const f4*)(fp0 + G3 + 4);
        float ca[8] = {a0[0], a0[1], a0[2], a0[3], a1[0], a1[1], a1[2], a1[3]};
        float cb[8] = {b0v[0], b0v[1], b0v[2], b0v[3],
                       b1v[0], b1v[1], b1v[2], b1v[3]};
#pragma unroll
        for (int vi = 0; vi < 8; ++vi) {
            h2 t2 = {(_Float16)ca[vi], (_Float16)cb[vi]};
            *(h2*)(Y + (vi * 8 + n) * KP + 64 + cp) = t2;
        }
    }
    if (tid < 64)
        mval[tid] = mask[((b * 8 + (tid & 7)) << 15) + v0 + (tid >> 3)];
    __syncthreads();

    // ---- rde MLP (fp32 VALU), RMW into Y[64:96); wt, sA --------------------
    {
        const int col = tid & 63;
        const int half = tid >> 6;      // each half does 16 of 32 outputs
        const int n = col & 7, vi = col >> 3;
        const int bn = b * 8 + n, v = v0 + vi;
        const float r0 = vdir[(bn * 3 + 0) * G3 + v];
        const float r1 = vdir[(bn * 3 + 1) * G3 + v];
        const float r2 = vdir[(bn * 3 + 2) * G3 + v];
        const float r3 = vdepth[bn * G3 + v];
        float h16[16];
#pragma unroll
        for (int o = 0; o < 16; ++o) {
            float a = rde_b1[o] + rde_w1[o * 4 + 0] * r0 +
                      rde_w1[o * 4 + 1] * r1 + rde_w1[o * 4 + 2] * r2 +
                      rde_w1[o * 4 + 3] * r3;
            h16[o] = eluf(a);
        }
        if (half == 0) {
            float msum = 0.f;
#pragma unroll
            for (int k = 0; k < 8; ++k) msum += mval[vi * 8 + k];
            const float inv = 1.0f / (msum + 1e-8f);
            wtc[col] = mval[col] * inv;
            if (n == 0) sA_v[vi] = msum * inv;
        }
        _Float16* yc = Y + col * KP + 64 + half * 16;
#pragma unroll
        for (int og = 0; og < 2; ++og) {
            h8 cur = *(h8*)(yc + og * 8);
#pragma unroll
            for (int oo = 0; oo < 8; ++oo) {
                const int o = half * 16 + og * 8 + oo;
                float a = rde_b2[o];
#pragma unroll
                for (int c = 0; c < 16; ++c) a += rde_w2[o * 16 + c] * h16[c];
                cur[oo] = (_Float16)((float)cur[oo] + eluf(a));
            }
            *(h8*)(yc + og * 8) = cur;
        }
    }
    __syncthreads();

    // ---- mask-weighted mean/var (single pass, h2) -> Y[0:32),[32:64) -------
    {
        const int vi = tid >> 4, cp = (tid & 15) * 2;
        float s0 = 0.f, s1 = 0.f, q0 = 0.f, q1 = 0.f;
#pragma unroll
        for (int n = 0; n < 8; ++n) {
            const int col = vi * 8 + n;
            h2 xv = *(const h2*)(Y + col * KP + 64 + cp);
            const float wv = wtc[col];
            const float x0 = (float)xv[0], x1 = (float)xv[1];
            s0 += wv * x0; q0 += wv * x0 * x0;
            s1 += wv * x1; q1 += wv * x1 * x1;
        }
        const float k = 2.0f - sA_v[vi];
        h2 hm = {(_Float16)s0, (_Float16)s1};
        h2 hv = {(_Float16)(q0 - s0 * s0 * k), (_Float16)(q1 - s1 * s1 * k)};
#pragma unroll
        for (int n = 0; n < 8; ++n) {
            *(h2*)(Y + (vi * 8 + n) * KP + cp) = hm;
            *(h2*)(Y + (vi * 8 + n) * KP + 32 + cp) = hv;
        }
    }
    __syncthreads();

    // ---- base1: 96 -> 64 (reads [0:96), writes [0:64): overlap -> barrier)--
    {
        f4 acc[2][4] = {};
        mfma_layer<96, 3, 4>(base_w1, Y, 0, 1 << 30, wave, lane, acc);
        __syncthreads();
        epi_store<4>(acc, base_b1, Y, 0, wave, lane);
    }
    __syncthreads();

    // ---- base2: 64 -> 32; x -> [64:96), x*wt -> [0:32) ---------------------
    {
        f4 acc[2][4] = {};
        mfma_layer<64, 2, 2>(base_w2, Y, 0, 1 << 30, wave, lane, acc);
        __syncthreads();
        const int q = lane >> 4, nlo = lane & 15;
#pragma unroll
        for (int j = 0; j < 2; ++j) {
            const int col = (wave * 2 + j) * 16 + nlo;
            const float wt = wtc[col];
#pragma unroll
            for (int mt = 0; mt < 2; ++mt) {
                f4 bbv = *(const f4*)(base_b2 + mt * 16 + q * 4);
                f4 v = acc[j][mt];
                h4 hx, hxw;
#pragma unroll
                for (int r = 0; r < 4; ++r) {
                    const float xv = eluf(v[r] + bbv[r]);
                    hx[r] = (_Float16)xv;
                    hxw[r] = (_Float16)(xv * wt);
                }
                *(h4*)(Y + col * KP + 64 + mt * 16 + q * 4) = hx;
                *(h4*)(Y + col * KP + mt * 16 + q * 4) = hxw;
            }
        }
    }
    __syncthreads();

    // ---- vis1: 32 -> 32 (reads [0:32), writes [32:64): disjoint) -----------
    {
        f4 acc[2][4] = {};
        mfma_layer<32, 1, 2>(vis_w1, Y, 0, 1 << 30, wave, lane, acc);
        epi_store<2>(acc, vis_b1, Y, 32, wave, lane);
    }
    __syncthreads();

    // ---- vis2: 32 -> 33 (reads [32:64), writes [0:32): disjoint) -----------
    {
        f4 acc[2][4] = {};
        mfma_layer<32, 1, 3>(vis_w2, Y, 32, 33, wave, lane, acc);
        const int q = lane >> 4, nlo = lane & 15;
#pragma unroll
        for (int j = 0; j < 2; ++j) {
            const int col = (wave * 2 + j) * 16 + nlo;
#pragma unroll
            for (int mt = 0; mt < 2; ++mt) {
                f4 bbv = *(const f4*)(vis_b2 + mt * 16 + q * 4);
                f4 v = acc[j][mt];
                h4 hv;
#pragma unroll
                for (int r = 0; r < 4; ++r)
                    hv[r] = (_Float16)eluf(v[r] + bbv[r]);
                *(h4*)(Y + col * KP + mt * 16 + q * 4) = hv;
            }
            if (q == 0) {  // global row 32: the vis channel
                const float vv = acc[j][2][0] + vis_b2[32];
                visn_s[col] = sigmoidf(eluf(vv)) * mval[col];
            }
        }
    }
    __syncthreads();

    // ---- x update: x += x_res -> [64:96), x*visn -> [0:32) (h2) ------------
    {
        const int n = tid >> 4, cp = (tid & 15) * 2;
#pragma unroll
        for (int vi = 0; vi < 8; ++vi) {
            const int col = vi * 8 + n;
            h2 xr = *(const h2*)(Y + col * KP + cp);
            h2 xo = *(const h2*)(Y + col * KP + 64 + cp);
            const float vn = visn_s[col];
            const float x0 = (float)xo[0] + (float)xr[0];
            const float x1 = (float)xo[1] + (float)xr[1];
            h2 hx = {(_Float16)x0, (_Float16)x1};
            h2 hxv = {(_Float16)(x0 * vn), (_Float16)(x1 * vn)};
            *(h2*)(Y + col * KP + 64 + cp) = hx;
            *(h2*)(Y + col * KP + cp) = hxv;
        }
    }
    __syncthreads();

    // ---- vis2_1: 32 -> 32 (reads [0:32), writes [32:64): disjoint) ---------
    {
        f4 acc[2][4] = {};
        mfma_layer<32, 1, 2>(vis2_w1, Y, 0, 1 << 30, wave, lane, acc);
        epi_store<2>(acc, vis2_b1, Y, 32, wave, lane);
    }
    __syncthreads();

    // ---- vis2_2 (1x32, VALU) -> visv ---------------------------------------
    if (tid < 64) {
        const _Float16* yc = Y + tid * KP + 32;
        float a0 = vis2_b2[0], a1 = 0.f;
#pragma unroll
        for (int c = 0; c < 32; c += 4) {
            h2 p0 = *(const h2*)(yc + c);
            h2 p1 = *(const h2*)(yc + c + 2);
            a0 += vis2_w2[c + 0] * (float)p0[0] + vis2_w2[c + 1] * (float)p0[1];
            a1 += vis2_w2[c + 2] * (float)p1[0] + vis2_w2[c + 3] * (float)p1[1];
        }
        visv_s[tid] = sigmoidf(a0 + a1) * mval[tid];
    }
    __syncthreads();
    if (tid < 64) {
        const int vi = tid >> 3, n = tid & 7;
        float b0 = 0.f;
#pragma unroll
        for (int k = 0; k < 8; ++k) b0 += visv_s[vi * 8 + k];
        const float inv = 1.0f / (b0 + 1e-8f);
        wt2c[tid] = visv_s[tid] * inv;
        if (n == 0) wm_v[vi] = b0 * inv * 0.125f;
    }
    __syncthreads();

    // ---- vis-weighted mean2/var2 (fp32) -> stats ---------------------------
    {
        const int vi = tid >> 4, cp = (tid & 15) * 2;
        float s0 = 0.f, s1 = 0.f, q0 = 0.f, q1 = 0.f;
#pragma unroll
        for (int n = 0; n < 8; ++n) {
            const int col = vi * 8 + n;
            h2 xv = *(const h2*)(Y + col * KP + 64 + cp);
            const float wv = wt2c[col];
            const float x0 = (float)xv[0], x1 = (float)xv[1];
            s0 += wv * x0; q0 += wv * x0 * x0;
            s1 += wv * x1; q1 += wv * x1 * x1;
        }
        const float sC = wm_v[vi] * 8.0f;
        const float k = 2.0f - sC;
        f2 mpair = {s0, s1};
        f2 vpair = {q0 - s0 * s0 * k, q1 - s1 * s1 * k};
        *(f2*)(stats + vi * 66 + cp) = mpair;
        *(f2*)(stats + vi * 66 + 32 + cp) = vpair;
        if (cp == 0) stats[vi * 66 + 64] = wm_v[vi];
    }
    __syncthreads();

    // ---- stat layer (VALU): o-major, 2 voxels/thread, coalesced f2 stores --
    {
        const int o = tid >> 2;            // 0..31
        const int vi0 = (tid & 3) * 2;     // 0,2,4,6
        const float* row = stat_w + o * 65;
        const float* sa = stats + vi0 * 66;
        const float* sb = stats + (vi0 + 1) * 66;
        float p0 = stat_b[o], p1 = p0, p2 = 0.f, p3 = 0.f;
#pragma unroll
        for (int c = 0; c < 32; c += 2) {
            const float w0 = row[c], w1 = row[c + 1];
            const float u0 = row[32 + c], u1 = row[32 + c + 1];
            p0 += w0 * sa[c] + u0 * sa[32 + c];
            p2 += w1 * sa[c + 1] + u1 * sa[32 + c + 1];
            p1 += w0 * sb[c] + u0 * sb[32 + c];
            p3 += w1 * sb[c + 1] + u1 * sb[32 + c + 1];
        }
        const float wlast = row[64];
        f2 r = {eluf(p0 + p2 + wlast * sa[64]), eluf(p1 + p3 + wlast * sb[64])};
        *(f2*)(out + ((b * 32 + o) << 15) + v0 + vi0) = r;
    }
}

extern "C" void kernel_launch(void* const* d_in, const int* in_sizes, int n_in,
                              void* d_out, int out_size, void* d_ws,
                              size_t ws_size, hipStream_t stream) {
    const float* features = (const float*)d_in[0];
    const float* mask = (const float*)d_in[1];
    const float* vdepth = (const float*)d_in[2];
    const float* vdir = (const float*)d_in[3];
    const float* rde_w1 = (const float*)d_in[4];
    const float* rde_b1 = (const float*)d_in[5];
    const float* rde_w2 = (const float*)d_in[6];
    const float* rde_b2 = (const float*)d_in[7];
    const float* base_w1 = (const float*)d_in[8];
    const float* base_b1 = (const float*)d_in[9];
    const float* base_w2 = (const float*)d_in[10];
    const float* base_b2 = (const float*)d_in[11];
    const float* vis_w1 = (const float*)d_in[12];
    const float* vis_b1 = (const float*)d_in[13];
    const float* vis_w2 = (const float*)d_in[14];
    const float* vis_b2 = (const float*)d_in[15];
    const float* vis2_w1 = (const float*)d_in[16];
    const float* vis2_b1 = (const float*)d_in[17];
    const float* vis2_w2 = (const float*)d_in[18];
    const float* vis2_b2 = (const float*)d_in[19];
    const float* stat_w = (const float*)d_in[20];
    const float* stat_b = (const float*)d_in[21];

    // 524288 cols / 64 per block = 8192 blocks, 128 threads (2 waves)
    ibr_mfma<<<8192, 128, 0, stream>>>(
        features, mask, vdepth, vdir, rde_w1, rde_b1, rde_w2, rde_b2, base_w1,
        base_b1, base_w2, base_b2, vis_w1, vis_b1, vis_w2, vis_b2, vis2_w1,
        vis2_b1, vis2_w2, vis2_b2, stat_w, stat_b, (float*)d_out);
}

// Round 7
// 222.550 us; speedup vs baseline: 1.2922x; 1.2922x over previous
//
#include <hip/hip_runtime.h>

// IBRNet aggregator R7: single-wave blocks, BARRIER-FREE fused MFMA chain.
// Block = 64 threads = 1 wave = 64 cols = 8 voxels x 8 views.
// col == lane, col = n*8 + vi (n = lane>>3 view, vi = lane&7 voxel).
//   -> VALU phases index lanes as (pv=lane>>3 voxel, u=lane&7): Y-bank =
//      vi*52 mod 32 = vi*20 (8 distinct) + u -> 2-way max (free).
//   -> view reductions = shfl_xor {8,16,32}.
// Y[col][k] f16, KP=104 (16B-aligned rows, 20 mod 32 dword stride).
// Weights f16-preconverted into d_ws by prep kernel (~5us, L1-hot frags).
// Cross-lane LDS dependencies rely on in-order per-wave DS execution +
// __builtin_amdgcn_wave_barrier() as a compiler code-motion fence: no
// s_barrier, no forced vmcnt(0) drains -> weight loads pipeline freely.
//
// Y slot timeline (k f16-ranges):
//   P0: per-lane rde MLP (registers) + features -> f -> [64:96)
//   P1: mask-weighted mean->[0:32) var->[32:64)  (broadcast to 8 cols)
//   P2: base1 96->64 reads [0:96) writes [0:64)
//   P3: base2 64->32: x->[64:96), x*wt->[0:32)
//   P4: vis1 32->32 reads [0:32) -> [32:64)
//   P5: vis2 32->33 reads [32:64) -> x_res [0:32), visn (row 32)
//   P6: x += x_res -> [64:96), x*visn -> [0:32)
//   P7: vis2_1 reads [0:32) -> [32:64)
//   P8: vis2_2 (VALU) -> visv -> wt2
//   P9: mean2/var2 (fp32) -> stats[8][72]
//   P10: stat layer (VALU) -> out (f4 stores)

#define G3 32768
#define KP 104
#define SST 72

typedef _Float16 h8 __attribute__((ext_vector_type(8)));
typedef _Float16 h4 __attribute__((ext_vector_type(4)));
typedef _Float16 h2 __attribute__((ext_vector_type(2)));
typedef float f4 __attribute__((ext_vector_type(4)));
typedef float f2 __attribute__((ext_vector_type(2)));
typedef float f4a __attribute__((ext_vector_type(4), aligned(4)));

#define WB() __builtin_amdgcn_wave_barrier()

__device__ __forceinline__ float eluf(float x) {
    return x > 0.0f ? x : __expf(x) - 1.0f;
}
__device__ __forceinline__ float sigmoidf(float x) {
    return 1.0f / (1.0f + __expf(-x));
}
__device__ __forceinline__ float red8v(float v) {
    v += __shfl_xor(v, 8, 64);
    v += __shfl_xor(v, 16, 64);
    v += __shfl_xor(v, 32, 64);
    return v;
}

// d_ws layout (f16 element offsets)
#define WS_BW1 0       // base_w1 [64][96]
#define WS_BW2 6144    // base_w2 [32][64]
#define WS_VW1 8192    // vis_w1  [32][32]
#define WS_VW2 9216    // vis_w2  [48][32], rows 33..47 zeroed
#define WS_V2W1 10752  // vis2_w1 [32][32]

__global__ void prep_kernel(const float* __restrict__ bw1,
                            const float* __restrict__ bw2,
                            const float* __restrict__ vw1,
                            const float* __restrict__ vw2,
                            const float* __restrict__ v2w1,
                            _Float16* __restrict__ wh) {
    int t = blockIdx.x * blockDim.x + threadIdx.x;
    int stride = gridDim.x * blockDim.x;
    for (int i = t; i < 6144; i += stride) wh[WS_BW1 + i] = (_Float16)bw1[i];
    for (int i = t; i < 2048; i += stride) wh[WS_BW2 + i] = (_Float16)bw2[i];
    for (int i = t; i < 1024; i += stride) wh[WS_VW1 + i] = (_Float16)vw1[i];
    for (int i = t; i < 1536; i += stride)
        wh[WS_VW2 + i] = (i < 1056) ? (_Float16)vw2[i] : (_Float16)0.0f;
    for (int i = t; i < 1024; i += stride) wh[WS_V2W1 + i] = (_Float16)v2w1[i];
}

// One 2-tile pass of a layer: tiles {pass*2, pass*2+1}, MT M-tiles of 16.
template <int K, int KS, int MT>
__device__ __forceinline__ void mfma_pass(const _Float16* __restrict__ Wf,
                                          const _Float16* __restrict__ Y,
                                          int srck0, int pass, int lane,
                                          f4 acc[2][4]) {
    const int q = lane >> 4, nlo = lane & 15;
    h8 bf[2][KS];
#pragma unroll
    for (int j = 0; j < 2; ++j) {
        const _Float16* yc =
            Y + ((pass * 2 + j) * 16 + nlo) * KP + srck0 + q * 8;
#pragma unroll
        for (int kt = 0; kt < KS; ++kt) bf[j][kt] = *(const h8*)(yc + kt * 32);
    }
#pragma unroll
    for (int mt = 0; mt < MT; ++mt) {
        h8 af[KS];
#pragma unroll
        for (int kt = 0; kt < KS; ++kt)
            af[kt] = *(const h8*)(Wf + (mt * 16 + nlo) * K + q * 8 + kt * 32);
#pragma unroll
        for (int j = 0; j < 2; ++j)
#pragma unroll
            for (int kt = 0; kt < KS; ++kt)
                acc[j][mt] = __builtin_amdgcn_mfma_f32_16x16x32_f16(
                    af[kt], bf[j][kt], acc[j][mt], 0, 0, 0);
    }
}

template <int MT>
__device__ __forceinline__ void epi_pass(f4 acc[2][4],
                                         const float* __restrict__ bias,
                                         _Float16* __restrict__ Y, int dstk0,
                                         int pass, int lane) {
    const int q = lane >> 4, nlo = lane & 15;
#pragma unroll
    for (int j = 0; j < 2; ++j) {
        const int col = (pass * 2 + j) * 16 + nlo;
#pragma unroll
        for (int mt = 0; mt < MT; ++mt) {
            f4 bb = *(const f4*)(bias + mt * 16 + q * 4);
            h4 hv;
#pragma unroll
            for (int r = 0; r < 4; ++r)
                hv[r] = (_Float16)eluf(acc[j][mt][r] + bb[r]);
            *(h4*)(Y + col * KP + dstk0 + mt * 16 + q * 4) = hv;
        }
    }
}

__global__ __launch_bounds__(64) void ibr_mfma(
    const float* __restrict__ features, const float* __restrict__ mask,
    const float* __restrict__ vdepth, const float* __restrict__ vdir,
    const float* __restrict__ rde_w1, const float* __restrict__ rde_b1,
    const float* __restrict__ rde_w2, const float* __restrict__ rde_b2,
    const float* __restrict__ base_b1, const float* __restrict__ base_b2,
    const float* __restrict__ vis_b1, const float* __restrict__ vis_b2,
    const float* __restrict__ vis2_b1, const float* __restrict__ vis2_w2,
    const float* __restrict__ vis2_b2, const float* __restrict__ stat_w,
    const float* __restrict__ stat_b, const _Float16* __restrict__ wh,
    float* __restrict__ out) {
    __shared__ _Float16 Y[64 * KP];  // 13312 B
    __shared__ float stats[8 * SST]; // 2304 B, stride 72 (8 mod 32)
    __shared__ float mval[64], wtc[64], visn_s[64], wt2c[64];
    __shared__ float sA_v[8], wm_v[8];

    const int lane = threadIdx.x;
    const int n = lane >> 3, vi = lane & 7;  // col == lane == n*8+vi
    const int blk = blockIdx.x;
    const int b = blk >> 12;
    const int i = blk & 4095;
    // XCD swizzle: same-XCD blocks (i&7) cover contiguous voxel spans.
    const int v0 = (((i & 7) << 9) | (i >> 3)) << 3;
    const int bn = b * 8 + n;
    const int v = v0 + vi;

    // ---- P0: loads, per-lane rde MLP, wt, f -> Y[64:96) --------------------
    const float m = mask[bn * G3 + v];
    const float r0 = vdir[(bn * 3 + 0) * G3 + v];
    const float r1 = vdir[(bn * 3 + 1) * G3 + v];
    const float r2 = vdir[(bn * 3 + 2) * G3 + v];
    const float r3 = vdepth[bn * G3 + v];
    float f[32];
#pragma unroll
    for (int c = 0; c < 32; ++c) f[c] = features[(bn * 32 + c) * G3 + v];

    float h16[16];
#pragma unroll
    for (int o = 0; o < 16; ++o) {
        float a = rde_b1[o] + rde_w1[o * 4 + 0] * r0 + rde_w1[o * 4 + 1] * r1 +
                  rde_w1[o * 4 + 2] * r2 + rde_w1[o * 4 + 3] * r3;
        h16[o] = eluf(a);
    }
#pragma unroll
    for (int o = 0; o < 32; ++o) {
        float a = rde_b2[o];
#pragma unroll
        for (int c = 0; c < 16; ++c) a += rde_w2[o * 16 + c] * h16[c];
        f[o] += eluf(a);
    }

    const float msum = red8v(m);
    const float invA = 1.0f / (msum + 1e-8f);
    const float wt = m * invA;
    mval[lane] = m;
    wtc[lane] = wt;
    if (lane < 8) sA_v[lane] = msum * invA;  // lanes<8: n=0, vi=lane

    {
        _Float16* yl = Y + lane * KP + 64;
#pragma unroll
        for (int g = 0; g < 4; ++g) {
            h8 t;
#pragma unroll
            for (int e = 0; e < 8; ++e) t[e] = (_Float16)f[g * 8 + e];
            *(h8*)(yl + g * 8) = t;
        }
    }
    WB();

    // ---- P1: mean->[0:32) var->[32:64), broadcast across the 8 views -------
    {
        const int pv = lane >> 3, u = lane & 7;
        const float kA = 2.0f - sA_v[pv];
#pragma unroll
        for (int t2 = 0; t2 < 2; ++t2) {
            const int dw = u + 8 * t2;  // channel-pair index 0..15
            float s0 = 0.f, s1 = 0.f, q0 = 0.f, q1 = 0.f;
#pragma unroll
            for (int nn = 0; nn < 8; ++nn) {
                const int col = nn * 8 + pv;
                h2 xv = *(const h2*)(Y + col * KP + 64 + dw * 2);
                const float wv = wtc[col];
                const float x0 = (float)xv[0], x1 = (float)xv[1];
                s0 += wv * x0; q0 += wv * x0 * x0;
                s1 += wv * x1; q1 += wv * x1 * x1;
            }
            h2 hm = {(_Float16)s0, (_Float16)s1};
            h2 hv = {(_Float16)(q0 - s0 * s0 * kA),
                     (_Float16)(q1 - s1 * s1 * kA)};
#pragma unroll
            for (int nn = 0; nn < 8; ++nn) {
                *(h2*)(Y + (nn * 8 + pv) * KP + dw * 2) = hm;
                *(h2*)(Y + (nn * 8 + pv) * KP + 32 + dw * 2) = hv;
            }
        }
    }
    WB();

    // ---- P2: base1 96 -> 64 ------------------------------------------------
#pragma unroll
    for (int pass = 0; pass < 2; ++pass) {
        f4 acc[2][4] = {};
        mfma_pass<96, 3, 4>(wh + WS_BW1, Y, 0, pass, lane, acc);
        epi_pass<4>(acc, base_b1, Y, 0, pass, lane);
    }
    WB();

    // ---- P3: base2 64 -> 32; x -> [64:96), x*wt -> [0:32) ------------------
#pragma unroll
    for (int pass = 0; pass < 2; ++pass) {
        f4 acc[2][4] = {};
        mfma_pass<64, 2, 2>(wh + WS_BW2, Y, 0, pass, lane, acc);
        const int q = lane >> 4, nlo = lane & 15;
#pragma unroll
        for (int j = 0; j < 2; ++j) {
            const int col = (pass * 2 + j) * 16 + nlo;
            const float w = wtc[col];
#pragma unroll
            for (int mt = 0; mt < 2; ++mt) {
                f4 bb = *(const f4*)(base_b2 + mt * 16 + q * 4);
                h4 hx, hxw;
#pragma unroll
                for (int r = 0; r < 4; ++r) {
                    const float xv = eluf(acc[j][mt][r] + bb[r]);
                    hx[r] = (_Float16)xv;
                    hxw[r] = (_Float16)(xv * w);
                }
                *(h4*)(Y + col * KP + 64 + mt * 16 + q * 4) = hx;
                *(h4*)(Y + col * KP + mt * 16 + q * 4) = hxw;
            }
        }
    }
    WB();

    // ---- P4: vis1 32 -> 32 -------------------------------------------------
#pragma unroll
    for (int pass = 0; pass < 2; ++pass) {
        f4 acc[2][4] = {};
        mfma_pass<32, 1, 2>(wh + WS_VW1, Y, 0, pass, lane, acc);
        epi_pass<2>(acc, vis_b1, Y, 32, pass, lane);
    }
    WB();

    // ---- P5: vis2 32 -> 33; x_res -> [0:32), visn --------------------------
#pragma unroll
    for (int pass = 0; pass < 2; ++pass) {
        f4 acc[2][4] = {};
        mfma_pass<32, 1, 3>(wh + WS_VW2, Y, 32, pass, lane, acc);
        const int q = lane >> 4, nlo = lane & 15;
#pragma unroll
        for (int j = 0; j < 2; ++j) {
            const int col = (pass * 2 + j) * 16 + nlo;
#pragma unroll
            for (int mt = 0; mt < 2; ++mt) {
                f4 bb = *(const f4*)(vis_b2 + mt * 16 + q * 4);
                h4 hv;
#pragma unroll
                for (int r = 0; r < 4; ++r)
                    hv[r] = (_Float16)eluf(acc[j][mt][r] + bb[r]);
                *(h4*)(Y + col * KP + mt * 16 + q * 4) = hv;
            }
            if (q == 0) {  // global row 32: vis channel
                const float vv = acc[j][2][0] + vis_b2[32];
                visn_s[col] = sigmoidf(eluf(vv)) * mval[col];
            }
        }
    }
    WB();

    // ---- P6: x += x_res -> [64:96), x*visn -> [0:32) -----------------------
    {
        const int pv = lane >> 3, u = lane & 7;
#pragma unroll
        for (int nn = 0; nn < 8; ++nn) {
            const int col = nn * 8 + pv;
            const float vn = visn_s[col];
#pragma unroll
            for (int t2 = 0; t2 < 2; ++t2) {
                const int dw = u + 8 * t2;
                h2 xr = *(const h2*)(Y + col * KP + dw * 2);
                h2 xo = *(const h2*)(Y + col * KP + 64 + dw * 2);
                const float x0 = (float)xo[0] + (float)xr[0];
                const float x1 = (float)xo[1] + (float)xr[1];
                h2 hx = {(_Float16)x0, (_Float16)x1};
                h2 hxv = {(_Float16)(x0 * vn), (_Float16)(x1 * vn)};
                *(h2*)(Y + col * KP + 64 + dw * 2) = hx;
                *(h2*)(Y + col * KP + dw * 2) = hxv;
            }
        }
    }
    WB();

    // ---- P7: vis2_1 32 -> 32 -----------------------------------------------
#pragma unroll
    for (int pass = 0; pass < 2; ++pass) {
        f4 acc[2][4] = {};
        mfma_pass<32, 1, 2>(wh + WS_V2W1, Y, 0, pass, lane, acc);
        epi_pass<2>(acc, vis2_b1, Y, 32, pass, lane);
    }
    WB();

    // ---- P8: vis2_2 (VALU, own col) -> visv, wt2 ---------------------------
    {
        const _Float16* yc = Y + lane * KP + 32;
        float a0 = vis2_b2[0], a1 = 0.f;
#pragma unroll
        for (int t = 0; t < 16; ++t) {
            h2 p = *(const h2*)(yc + t * 2);
            if (t & 1)
                a1 += vis2_w2[t * 2] * (float)p[0] +
                      vis2_w2[t * 2 + 1] * (float)p[1];
            else
                a0 += vis2_w2[t * 2] * (float)p[0] +
                      vis2_w2[t * 2 + 1] * (float)p[1];
        }
        const float visv = sigmoidf(a0 + a1) * m;
        const float b0 = red8v(visv);
        const float invC = 1.0f / (b0 + 1e-8f);
        wt2c[lane] = visv * invC;
        if (lane < 8) wm_v[lane] = b0 * invC * 0.125f;
    }
    WB();

    // ---- P9: vis-weighted mean2/var2 (fp32) -> stats -----------------------
    {
        const int pv = lane >> 3, u = lane & 7;
        const float sC = wm_v[pv] * 8.0f;
        const float kC = 2.0f - sC;
#pragma unroll
        for (int t2 = 0; t2 < 2; ++t2) {
            const int dw = u + 8 * t2;
            float s0 = 0.f, s1 = 0.f, q0 = 0.f, q1 = 0.f;
#pragma unroll
            for (int nn = 0; nn < 8; ++nn) {
                const int col = nn * 8 + pv;
                h2 xv = *(const h2*)(Y + col * KP + 64 + dw * 2);
                const float wv = wt2c[col];
                const float x0 = (float)xv[0], x1 = (float)xv[1];
                s0 += wv * x0; q0 += wv * x0 * x0;
                s1 += wv * x1; q1 += wv * x1 * x1;
            }
            f2 mp = {s0, s1};
            f2 vp = {q0 - s0 * s0 * kC, q1 - s1 * s1 * kC};
            *(f2*)(stats + pv * SST + dw * 2) = mp;
            *(f2*)(stats + pv * SST + 32 + dw * 2) = vp;
        }
    }
    WB();

    // ---- P10: stat layer (VALU), lane = (o, half), 4 voxels/lane -----------
    {
        const int o = lane >> 1;
        const int vi0 = (lane & 1) * 4;
        const float* row = stat_w + o * 65;
        float pr[4];
#pragma unroll
        for (int k2 = 0; k2 < 4; ++k2) pr[k2] = stat_b[o];
#pragma unroll
        for (int c4 = 0; c4 < 8; ++c4) {
            f4a wr = *(const f4a*)(row + c4 * 4);
            f4a ur = *(const f4a*)(row + 32 + c4 * 4);
#pragma unroll
            for (int k2 = 0; k2 < 4; ++k2) {
                const float* sp = stats + (vi0 + k2) * SST + c4 * 4;
                f4 sm = *(const f4*)sp;
                f4 sv = *(const f4*)(sp + 32);
                pr[k2] += wr[0] * sm[0] + wr[1] * sm[1] + wr[2] * sm[2] +
                          wr[3] * sm[3] + ur[0] * sv[0] + ur[1] * sv[1] +
                          ur[2] * sv[2] + ur[3] * sv[3];
            }
        }
        const float wl = row[64];
        f4 res;
#pragma unroll
        for (int k2 = 0; k2 < 4; ++k2)
            res[k2] = eluf(pr[k2] + wl * wm_v[vi0 + k2]);
        *(f4*)(out + ((b * 32 + o) << 15) + v0 + vi0) = res;
    }
}

extern "C" void kernel_launch(void* const* d_in, const int* in_sizes, int n_in,
                              void* d_out, int out_size, void* d_ws,
                              size_t ws_size, hipStream_t stream) {
    const float* features = (const float*)d_in[0];
    const float* mask = (const float*)d_in[1];
    const float* vdepth = (const float*)d_in[2];
    const float* vdir = (const float*)d_in[3];
    const float* rde_w1 = (const float*)d_in[4];
    const float* rde_b1 = (const float*)d_in[5];
    const float* rde_w2 = (const float*)d_in[6];
    const float* rde_b2 = (const float*)d_in[7];
    const float* base_w1 = (const float*)d_in[8];
    const float* base_b1 = (const float*)d_in[9];
    const float* base_w2 = (const float*)d_in[10];
    const float* base_b2 = (const float*)d_in[11];
    const float* vis_w1 = (const float*)d_in[12];
    const float* vis_b1 = (const float*)d_in[13];
    const float* vis_w2 = (const float*)d_in[14];
    const float* vis_b2 = (const float*)d_in[15];
    const float* vis2_w1 = (const float*)d_in[16];
    const float* vis2_b1 = (const float*)d_in[17];
    const float* vis2_w2 = (const float*)d_in[18];
    const float* vis2_b2 = (const float*)d_in[19];
    const float* stat_w = (const float*)d_in[20];
    const float* stat_b = (const float*)d_in[21];

    _Float16* wh = (_Float16*)d_ws;
    prep_kernel<<<24, 256, 0, stream>>>(base_w1, base_w2, vis_w1, vis_w2,
                                        vis2_w1, wh);

    // 524288 cols / 64 per block = 8192 single-wave blocks
    ibr_mfma<<<8192, 64, 0, stream>>>(
        features, mask, vdepth, vdir, rde_w1, rde_b1, rde_w2, rde_b2, base_b1,
        base_b2, vis_b1, vis_b2, vis2_b1, vis2_w2, vis2_b2, stat_w, stat_b, wh,
        (float*)d_out);
}

// Round 8
// 202.546 us; speedup vs baseline: 1.4198x; 1.0988x over previous
//
#include <hip/hip_runtime.h>

// IBRNet aggregator R8: R7 (single-wave, barrier-free, n-major cols) with
// LDS cut to exactly Y = 13312 B -> 12 blocks/CU (was 16.9 KB -> 9).
//  - stats (mean2/var2) aliased into dead Y[0:64) slots of cols 0..15:
//    mean2[vi] at (float*)(Y + 2vi*KP), var2[vi] at (float*)(Y+(2vi+1)*KP).
//    Row stride 104 dwords == 8 mod 32 -> 2-way banked (free).
//  - per-col scalars {mval, wtc, visn, wt2c} live in the 16 B Y row gap
//    [96:104) (4 floats, exact fit).
//  - sA/wm (per-voxel) via __shfl from the lane that owns that voxel.
// Everything else identical to R7.
//
// Block = 64 threads = 1 wave = 64 cols = 8 voxels x 8 views.
// col == lane, col = n*8 + vi (n = lane>>3 view, vi = lane&7 voxel).
// view reductions = shfl_xor {8,16,32}. Y[col][k] f16, KP=104.
// Weights f16-preconverted into d_ws by prep kernel.
// Cross-lane LDS deps rely on in-order per-wave DS execution +
// __builtin_amdgcn_wave_barrier() as a compiler fence (no s_barrier).

#define G3 32768
#define KP 104

typedef _Float16 h8 __attribute__((ext_vector_type(8)));
typedef _Float16 h4 __attribute__((ext_vector_type(4)));
typedef _Float16 h2 __attribute__((ext_vector_type(2)));
typedef float f4 __attribute__((ext_vector_type(4)));
typedef float f2 __attribute__((ext_vector_type(2)));
typedef float f4a __attribute__((ext_vector_type(4), aligned(4)));

#define WB() __builtin_amdgcn_wave_barrier()

__device__ __forceinline__ float eluf(float x) {
    return x > 0.0f ? x : __expf(x) - 1.0f;
}
__device__ __forceinline__ float sigmoidf(float x) {
    return 1.0f / (1.0f + __expf(-x));
}
__device__ __forceinline__ float red8v(float v) {
    v += __shfl_xor(v, 8, 64);
    v += __shfl_xor(v, 16, 64);
    v += __shfl_xor(v, 32, 64);
    return v;
}

// d_ws layout (f16 element offsets)
#define WS_BW1 0       // base_w1 [64][96]
#define WS_BW2 6144    // base_w2 [32][64]
#define WS_VW1 8192    // vis_w1  [32][32]
#define WS_VW2 9216    // vis_w2  [48][32], rows 33..47 zeroed
#define WS_V2W1 10752  // vis2_w1 [32][32]

__global__ void prep_kernel(const float* __restrict__ bw1,
                            const float* __restrict__ bw2,
                            const float* __restrict__ vw1,
                            const float* __restrict__ vw2,
                            const float* __restrict__ v2w1,
                            _Float16* __restrict__ wh) {
    int t = blockIdx.x * blockDim.x + threadIdx.x;
    int stride = gridDim.x * blockDim.x;
    for (int i = t; i < 6144; i += stride) wh[WS_BW1 + i] = (_Float16)bw1[i];
    for (int i = t; i < 2048; i += stride) wh[WS_BW2 + i] = (_Float16)bw2[i];
    for (int i = t; i < 1024; i += stride) wh[WS_VW1 + i] = (_Float16)vw1[i];
    for (int i = t; i < 1536; i += stride)
        wh[WS_VW2 + i] = (i < 1056) ? (_Float16)vw2[i] : (_Float16)0.0f;
    for (int i = t; i < 1024; i += stride) wh[WS_V2W1 + i] = (_Float16)v2w1[i];
}

// One 2-tile pass of a layer: tiles {pass*2, pass*2+1}, MT M-tiles of 16.
template <int K, int KS, int MT>
__device__ __forceinline__ void mfma_pass(const _Float16* __restrict__ Wf,
                                          const _Float16* __restrict__ Y,
                                          int srck0, int pass, int lane,
                                          f4 acc[2][4]) {
    const int q = lane >> 4, nlo = lane & 15;
    h8 bf[2][KS];
#pragma unroll
    for (int j = 0; j < 2; ++j) {
        const _Float16* yc =
            Y + ((pass * 2 + j) * 16 + nlo) * KP + srck0 + q * 8;
#pragma unroll
        for (int kt = 0; kt < KS; ++kt) bf[j][kt] = *(const h8*)(yc + kt * 32);
    }
#pragma unroll
    for (int mt = 0; mt < MT; ++mt) {
        h8 af[KS];
#pragma unroll
        for (int kt = 0; kt < KS; ++kt)
            af[kt] = *(const h8*)(Wf + (mt * 16 + nlo) * K + q * 8 + kt * 32);
#pragma unroll
        for (int j = 0; j < 2; ++j)
#pragma unroll
            for (int kt = 0; kt < KS; ++kt)
                acc[j][mt] = __builtin_amdgcn_mfma_f32_16x16x32_f16(
                    af[kt], bf[j][kt], acc[j][mt], 0, 0, 0);
    }
}

template <int MT>
__device__ __forceinline__ void epi_pass(f4 acc[2][4],
                                         const float* __restrict__ bias,
                                         _Float16* __restrict__ Y, int dstk0,
                                         int pass, int lane) {
    const int q = lane >> 4, nlo = lane & 15;
#pragma unroll
    for (int j = 0; j < 2; ++j) {
        const int col = (pass * 2 + j) * 16 + nlo;
#pragma unroll
        for (int mt = 0; mt < MT; ++mt) {
            f4 bb = *(const f4*)(bias + mt * 16 + q * 4);
            h4 hv;
#pragma unroll
            for (int r = 0; r < 4; ++r)
                hv[r] = (_Float16)eluf(acc[j][mt][r] + bb[r]);
            *(h4*)(Y + col * KP + dstk0 + mt * 16 + q * 4) = hv;
        }
    }
}

__global__ __launch_bounds__(64) void ibr_mfma(
    const float* __restrict__ features, const float* __restrict__ mask,
    const float* __restrict__ vdepth, const float* __restrict__ vdir,
    const float* __restrict__ rde_w1, const float* __restrict__ rde_b1,
    const float* __restrict__ rde_w2, const float* __restrict__ rde_b2,
    const float* __restrict__ base_b1, const float* __restrict__ base_b2,
    const float* __restrict__ vis_b1, const float* __restrict__ vis_b2,
    const float* __restrict__ vis2_b1, const float* __restrict__ vis2_w2,
    const float* __restrict__ vis2_b2, const float* __restrict__ stat_w,
    const float* __restrict__ stat_b, const _Float16* __restrict__ wh,
    float* __restrict__ out) {
    __shared__ _Float16 Y[64 * KP];  // 13312 B -- the ONLY LDS

// per-col scalar gap: {mval, wtc, visn, wt2c} at Y row tail [96:104)
#define GAPF(col) ((float*)(Y + (col)*KP + 96))

    const int lane = threadIdx.x;
    const int n = lane >> 3, vi = lane & 7;  // col == lane == n*8+vi
    const int blk = blockIdx.x;
    const int b = blk >> 12;
    const int i = blk & 4095;
    // XCD swizzle: same-XCD blocks (i&7) cover contiguous voxel spans.
    const int v0 = (((i & 7) << 9) | (i >> 3)) << 3;
    const int bn = b * 8 + n;
    const int v = v0 + vi;

    // ---- P0: loads, per-lane rde MLP, wt, f -> Y[64:96) --------------------
    const float m = mask[bn * G3 + v];
    const float r0 = vdir[(bn * 3 + 0) * G3 + v];
    const float r1 = vdir[(bn * 3 + 1) * G3 + v];
    const float r2 = vdir[(bn * 3 + 2) * G3 + v];
    const float r3 = vdepth[bn * G3 + v];
    float f[32];
#pragma unroll
    for (int c = 0; c < 32; ++c) f[c] = features[(bn * 32 + c) * G3 + v];

    float h16[16];
#pragma unroll
    for (int o = 0; o < 16; ++o) {
        float a = rde_b1[o] + rde_w1[o * 4 + 0] * r0 + rde_w1[o * 4 + 1] * r1 +
                  rde_w1[o * 4 + 2] * r2 + rde_w1[o * 4 + 3] * r3;
        h16[o] = eluf(a);
    }
#pragma unroll
    for (int o = 0; o < 32; ++o) {
        float a = rde_b2[o];
#pragma unroll
        for (int c = 0; c < 16; ++c) a += rde_w2[o * 16 + c] * h16[c];
        f[o] += eluf(a);
    }

    const float msum = red8v(m);
    const float invA = 1.0f / (msum + 1e-8f);
    const float wt = m * invA;
    const float sA = msum * invA;  // own-voxel sum of weights
    {
        f2 mw = {m, wt};
        *(f2*)GAPF(lane) = mw;  // gap[0]=mval, gap[1]=wtc
    }

    {
        _Float16* yl = Y + lane * KP + 64;
#pragma unroll
        for (int g = 0; g < 4; ++g) {
            h8 t;
#pragma unroll
            for (int e = 0; e < 8; ++e) t[e] = (_Float16)f[g * 8 + e];
            *(h8*)(yl + g * 8) = t;
        }
    }
    WB();

    // ---- P1: mean->[0:32) var->[32:64), broadcast across the 8 views -------
    {
        const int pv = lane >> 3, u = lane & 7;
        const float kA = 2.0f - __shfl(sA, pv, 64);  // lane pv owns vi=pv
#pragma unroll
        for (int t2 = 0; t2 < 2; ++t2) {
            const int dw = u + 8 * t2;  // channel-pair index 0..15
            float s0 = 0.f, s1 = 0.f, q0 = 0.f, q1 = 0.f;
#pragma unroll
            for (int nn = 0; nn < 8; ++nn) {
                const int col = nn * 8 + pv;
                h2 xv = *(const h2*)(Y + col * KP + 64 + dw * 2);
                const float wv = GAPF(col)[1];
                const float x0 = (float)xv[0], x1 = (float)xv[1];
                s0 += wv * x0; q0 += wv * x0 * x0;
                s1 += wv * x1; q1 += wv * x1 * x1;
            }
            h2 hm = {(_Float16)s0, (_Float16)s1};
            h2 hv = {(_Float16)(q0 - s0 * s0 * kA),
                     (_Float16)(q1 - s1 * s1 * kA)};
#pragma unroll
            for (int nn = 0; nn < 8; ++nn) {
                *(h2*)(Y + (nn * 8 + pv) * KP + dw * 2) = hm;
                *(h2*)(Y + (nn * 8 + pv) * KP + 32 + dw * 2) = hv;
            }
        }
    }
    WB();

    // ---- P2: base1 96 -> 64 ------------------------------------------------
#pragma unroll
    for (int pass = 0; pass < 2; ++pass) {
        f4 acc[2][4] = {};
        mfma_pass<96, 3, 4>(wh + WS_BW1, Y, 0, pass, lane, acc);
        epi_pass<4>(acc, base_b1, Y, 0, pass, lane);
    }
    WB();

    // ---- P3: base2 64 -> 32; x -> [64:96), x*wt -> [0:32) ------------------
#pragma unroll
    for (int pass = 0; pass < 2; ++pass) {
        f4 acc[2][4] = {};
        mfma_pass<64, 2, 2>(wh + WS_BW2, Y, 0, pass, lane, acc);
        const int q = lane >> 4, nlo = lane & 15;
#pragma unroll
        for (int j = 0; j < 2; ++j) {
            const int col = (pass * 2 + j) * 16 + nlo;
            const float w = GAPF(col)[1];
#pragma unroll
            for (int mt = 0; mt < 2; ++mt) {
                f4 bb = *(const f4*)(base_b2 + mt * 16 + q * 4);
                h4 hx, hxw;
#pragma unroll
                for (int r = 0; r < 4; ++r) {
                    const float xv = eluf(acc[j][mt][r] + bb[r]);
                    hx[r] = (_Float16)xv;
                    hxw[r] = (_Float16)(xv * w);
                }
                *(h4*)(Y + col * KP + 64 + mt * 16 + q * 4) = hx;
                *(h4*)(Y + col * KP + mt * 16 + q * 4) = hxw;
            }
        }
    }
    WB();

    // ---- P4: vis1 32 -> 32 -------------------------------------------------
#pragma unroll
    for (int pass = 0; pass < 2; ++pass) {
        f4 acc[2][4] = {};
        mfma_pass<32, 1, 2>(wh + WS_VW1, Y, 0, pass, lane, acc);
        epi_pass<2>(acc, vis_b1, Y, 32, pass, lane);
    }
    WB();

    // ---- P5: vis2 32 -> 33; x_res -> [0:32), visn --------------------------
#pragma unroll
    for (int pass = 0; pass < 2; ++pass) {
        f4 acc[2][4] = {};
        mfma_pass<32, 1, 3>(wh + WS_VW2, Y, 32, pass, lane, acc);
        const int q = lane >> 4, nlo = lane & 15;
#pragma unroll
        for (int j = 0; j < 2; ++j) {
            const int col = (pass * 2 + j) * 16 + nlo;
#pragma unroll
            for (int mt = 0; mt < 2; ++mt) {
                f4 bb = *(const f4*)(vis_b2 + mt * 16 + q * 4);
                h4 hv;
#pragma unroll
                for (int r = 0; r < 4; ++r)
                    hv[r] = (_Float16)eluf(acc[j][mt][r] + bb[r]);
                *(h4*)(Y + col * KP + mt * 16 + q * 4) = hv;
            }
            if (q == 0) {  // global row 32: vis channel
                const float vv = acc[j][2][0] + vis_b2[32];
                GAPF(col)[2] = sigmoidf(eluf(vv)) * GAPF(col)[0];
            }
        }
    }
    WB();

    // ---- P6: x += x_res -> [64:96), x*visn -> [0:32) -----------------------
    {
        const int pv = lane >> 3, u = lane & 7;
#pragma unroll
        for (int nn = 0; nn < 8; ++nn) {
            const int col = nn * 8 + pv;
            const float vn = GAPF(col)[2];
#pragma unroll
            for (int t2 = 0; t2 < 2; ++t2) {
                const int dw = u + 8 * t2;
                h2 xr = *(const h2*)(Y + col * KP + dw * 2);
                h2 xo = *(const h2*)(Y + col * KP + 64 + dw * 2);
                const float x0 = (float)xo[0] + (float)xr[0];
                const float x1 = (float)xo[1] + (float)xr[1];
                h2 hx = {(_Float16)x0, (_Float16)x1};
                h2 hxv = {(_Float16)(x0 * vn), (_Float16)(x1 * vn)};
                *(h2*)(Y + col * KP + 64 + dw * 2) = hx;
                *(h2*)(Y + col * KP + dw * 2) = hxv;
            }
        }
    }
    WB();

    // ---- P7: vis2_1 32 -> 32 -----------------------------------------------
#pragma unroll
    for (int pass = 0; pass < 2; ++pass) {
        f4 acc[2][4] = {};
        mfma_pass<32, 1, 2>(wh + WS_V2W1, Y, 0, pass, lane, acc);
        epi_pass<2>(acc, vis2_b1, Y, 32, pass, lane);
    }
    WB();

    // ---- P8: vis2_2 (VALU, own col) -> visv, wt2 ---------------------------
    float sCl;  // per-lane: sum of wt2 over views for its voxel
    {
        const _Float16* yc = Y + lane * KP + 32;
        float a0 = vis2_b2[0], a1 = 0.f;
#pragma unroll
        for (int t = 0; t < 16; ++t) {
            h2 p = *(const h2*)(yc + t * 2);
            if (t & 1)
                a1 += vis2_w2[t * 2] * (float)p[0] +
                      vis2_w2[t * 2 + 1] * (float)p[1];
            else
                a0 += vis2_w2[t * 2] * (float)p[0] +
                      vis2_w2[t * 2 + 1] * (float)p[1];
        }
        const float visv = sigmoidf(a0 + a1) * m;
        const float b0 = red8v(visv);
        const float invC = 1.0f / (b0 + 1e-8f);
        GAPF(lane)[3] = visv * invC;  // wt2
        sCl = b0 * invC;
    }
    WB();

    // ---- P9: vis-weighted mean2/var2 (fp32) -> aliased stats rows ----------
    // mean2[pv] -> (float*)(Y + (2pv)*KP)[0:32), var2[pv] -> +KP row.
    {
        const int pv = lane >> 3, u = lane & 7;
        const float kC = 2.0f - __shfl(sCl, pv, 64);
#pragma unroll
        for (int t2 = 0; t2 < 2; ++t2) {
            const int dw = u + 8 * t2;
            float s0 = 0.f, s1 = 0.f, q0 = 0.f, q1 = 0.f;
#pragma unroll
            for (int nn = 0; nn < 8; ++nn) {
                const int col = nn * 8 + pv;
                h2 xv = *(const h2*)(Y + col * KP + 64 + dw * 2);
                const float wv = GAPF(col)[3];
                const float x0 = (float)xv[0], x1 = (float)xv[1];
                s0 += wv * x0; q0 += wv * x0 * x0;
                s1 += wv * x1; q1 += wv * x1 * x1;
            }
            f2 mp = {s0, s1};
            f2 vp = {q0 - s0 * s0 * kC, q1 - s1 * s1 * kC};
            *(f2*)((float*)(Y + (2 * pv) * KP) + dw * 2) = mp;
            *(f2*)((float*)(Y + (2 * pv + 1) * KP) + dw * 2) = vp;
        }
    }
    WB();

    // ---- P10: stat layer (VALU), lane = (o, half), 4 voxels/lane -----------
    {
        const int o = lane >> 1;
        const int vi0 = (lane & 1) * 4;
        const float wm_own = sCl * 0.125f;  // own-voxel mean of weight
        const float* row = stat_w + o * 65;
        float wmv[4];
#pragma unroll
        for (int k2 = 0; k2 < 4; ++k2) wmv[k2] = __shfl(wm_own, vi0 + k2, 64);
        float pr[4];
#pragma unroll
        for (int k2 = 0; k2 < 4; ++k2) pr[k2] = stat_b[o];
#pragma unroll
        for (int c4 = 0; c4 < 8; ++c4) {
            f4a wr = *(const f4a*)(row + c4 * 4);
            f4a ur = *(const f4a*)(row + 32 + c4 * 4);
#pragma unroll
            for (int k2 = 0; k2 < 4; ++k2) {
                const float* sm = (const float*)(Y + (2 * (vi0 + k2)) * KP);
                const float* sv = (const float*)(Y + (2 * (vi0 + k2) + 1) * KP);
                f4 a = *(const f4*)(sm + c4 * 4);
                f4 bvv = *(const f4*)(sv + c4 * 4);
                pr[k2] += wr[0] * a[0] + wr[1] * a[1] + wr[2] * a[2] +
                          wr[3] * a[3] + ur[0] * bvv[0] + ur[1] * bvv[1] +
                          ur[2] * bvv[2] + ur[3] * bvv[3];
            }
        }
        const float wl = row[64];
        f4 res;
#pragma unroll
        for (int k2 = 0; k2 < 4; ++k2)
            res[k2] = eluf(pr[k2] + wl * wmv[k2]);
        *(f4*)(out + ((b * 32 + o) << 15) + v0 + vi0) = res;
    }
#undef GAPF
}

extern "C" void kernel_launch(void* const* d_in, const int* in_sizes, int n_in,
                              void* d_out, int out_size, void* d_ws,
                              size_t ws_size, hipStream_t stream) {
    const float* features = (const float*)d_in[0];
    const float* mask = (const float*)d_in[1];
    const float* vdepth = (const float*)d_in[2];
    const float* vdir = (const float*)d_in[3];
    const float* rde_w1 = (const float*)d_in[4];
    const float* rde_b1 = (const float*)d_in[5];
    const float* rde_w2 = (const float*)d_in[6];
    const float* rde_b2 = (const float*)d_in[7];
    const float* base_w1 = (const float*)d_in[8];
    const float* base_b1 = (const float*)d_in[9];
    const float* base_w2 = (const float*)d_in[10];
    const float* base_b2 = (const float*)d_in[11];
    const float* vis_w1 = (const float*)d_in[12];
    const float* vis_b1 = (const float*)d_in[13];
    const float* vis_w2 = (const float*)d_in[14];
    const float* vis_b2 = (const float*)d_in[15];
    const float* vis2_w1 = (const float*)d_in[16];
    const float* vis2_b1 = (const float*)d_in[17];
    const float* vis2_w2 = (const float*)d_in[18];
    const float* vis2_b2 = (const float*)d_in[19];
    const float* stat_w = (const float*)d_in[20];
    const float* stat_b = (const float*)d_in[21];

    _Float16* wh = (_Float16*)d_ws;
    prep_kernel<<<24, 256, 0, stream>>>(base_w1, base_w2, vis_w1, vis_w2,
                                        vis2_w1, wh);

    // 524288 cols / 64 per block = 8192 single-wave blocks
    ibr_mfma<<<8192, 64, 0, stream>>>(
        features, mask, vdepth, vdir, rde_w1, rde_b1, rde_w2, rde_b2, base_b1,
        base_b2, vis_b1, vis_b2, vis2_b1, vis2_w2, vis2_b2, stat_w, stat_b, wh,
        (float*)d_out);
}